// Round 5
// baseline (209.659 us; speedup 1.0000x reference)
//
#include <hip/hip_runtime.h>
#include <cstddef>

#define N_NODES_C 50000
#define N_EDGES_C 800000

typedef _Float16 f16x8 __attribute__((ext_vector_type(8)));
typedef float    f32x4 __attribute__((ext_vector_type(4)));

constexpr int XSTR = 72;           // f16 stride for per-wave h buffer
constexpr int MQ_BLOCKS   = 782;   // ceil(50000/64) compute blocks
constexpr int FILL_BLOCKS = 782;   // ceil(800000/1024), 4 edges/thread
constexpr int DEG_BLOCKS  = 782;   // ceil(800000/1024), 4 edges/thread

// ---------------------------------------------------------------------------
// prep (wT, W3T swizzled) + deg fused (4 shadow arrays, 4 edges/thread).
//  wT[l][j][k] = W_l[k][j] (f16)                      idx [0, 28672)
//  W3T[r=y*64+x][64 k] (f16), 16B chunks XOR-swizzled: chunk c of row r
//  stored at chunk c^(r&7). Value = w_out[k*2048 + r].   idx [28672, 159744)
//  Deg pass ALSO captures rank[e] = old count in shadow k = (e>>8)&3 —
//  this makes the CSR fill atomic-free (slot = shoff[k][col] + rank[e]).
// ---------------------------------------------------------------------------
__global__ void prep_deg_kernel(const float* __restrict__ w_in,
                                const float* __restrict__ w_mid,
                                const float* __restrict__ w_out,
                                const int* __restrict__ col,
                                _Float16* __restrict__ wT,
                                _Float16* __restrict__ W3T,
                                int* __restrict__ deg4,   // [4][N_NODES_C]
                                int* __restrict__ rank)   // [N_EDGES_C]
{
    const int b = blockIdx.x;
    if (b < 624) {
        const int idx = b * 256 + threadIdx.x;
        if (idx < 7 * 4096) {
            const int l = idx >> 12, rem = idx & 4095;
            const int j = rem >> 6, k = rem & 63;
            const float v = (l == 0) ? w_in[k * 64 + j]
                                     : w_mid[(size_t)(l - 1) * 4096 + k * 64 + j];
            wT[(size_t)l * 4096 + j * 64 + k] = (_Float16)v;
        } else {
            const int i2 = idx - 7 * 4096;   // < 131072
            const int r = i2 >> 6, k = i2 & 63;
            const int c = k >> 3;
            const int pos = ((c ^ (r & 7)) << 3) | (k & 7);
            W3T[(size_t)r * 64 + pos] = (_Float16)w_out[(size_t)k * 2048 + r];
        }
    } else {
        const int e0 = (b - 624) * 1024 + threadIdx.x;
        #pragma unroll
        for (int k = 0; k < 4; ++k) {
            const int e = e0 + k * 256;
            if (e < N_EDGES_C)
                rank[e] = atomicAdd(&deg4[k * N_NODES_C + col[e]], 1);
        }
    }
}

// ---------------------------------------------------------------------------
// 3-phase parallel scan over deg = sum of 4 shadows; scan3 also emits dinv
// and the per-shadow exclusive offsets shoff[k][i] used by the fill.
// ---------------------------------------------------------------------------
__global__ void scan1_kernel(const int* __restrict__ deg4, int* __restrict__ bsum)
{
    const int t = threadIdx.x;
    const int i = blockIdx.x * 256 + t;
    int v = 0;
    if (i < N_NODES_C) {
        #pragma unroll
        for (int k = 0; k < 4; ++k) v += deg4[k * N_NODES_C + i];
    }
    #pragma unroll
    for (int d = 1; d < 64; d <<= 1) v += __shfl_xor(v, d);
    __shared__ int s[4];
    if ((t & 63) == 0) s[t >> 6] = v;
    __syncthreads();
    if (t == 0) bsum[blockIdx.x] = s[0] + s[1] + s[2] + s[3];
}

__global__ void scan2_kernel(const int* __restrict__ bsum, int* __restrict__ boff,
                             int* __restrict__ rowptr)
{
    __shared__ int sh[256];
    const int t = threadIdx.x;
    const int v = (t < 196) ? bsum[t] : 0;
    sh[t] = v;
    __syncthreads();
    for (int d = 1; d < 256; d <<= 1) {
        const int u = (t >= d) ? sh[t - d] : 0;
        __syncthreads();
        sh[t] += u;
        __syncthreads();
    }
    if (t < 196) boff[t] = sh[t] - v;     // exclusive
    if (t == 0) rowptr[N_NODES_C] = N_EDGES_C;
}

__global__ void scan3_kernel(const int* __restrict__ deg4, const int* __restrict__ boff,
                             int* __restrict__ rowptr, int* __restrict__ shoff,
                             float* __restrict__ dinv)
{
    const int t = threadIdx.x;
    const int i = blockIdx.x * 256 + t;
    const int lane = t & 63, w = t >> 6;
    int d[4];
    int v = 0;
    if (i < N_NODES_C) {
        #pragma unroll
        for (int k = 0; k < 4; ++k) { d[k] = deg4[k * N_NODES_C + i]; v += d[k]; }
    } else {
        d[0] = d[1] = d[2] = d[3] = 0;
    }
    int inc = v;
    #pragma unroll
    for (int dd = 1; dd < 64; dd <<= 1) {
        const int u = __shfl_up(inc, dd);
        if (lane >= dd) inc += u;
    }
    __shared__ int ws[4];
    if (lane == 63) ws[w] = inc;
    __syncthreads();
    int wo = 0;
    #pragma unroll
    for (int k = 0; k < 4; ++k) if (k < w) wo += ws[k];
    const int excl = boff[blockIdx.x] + wo + inc - v;
    if (i < N_NODES_C) {
        rowptr[i] = excl;
        dinv[i] = (v > 0) ? rsqrtf((float)v) : 0.f;
        int o = excl;
        shoff[0 * N_NODES_C + i] = o; o += d[0];
        shoff[1 * N_NODES_C + i] = o; o += d[1];
        shoff[2 * N_NODES_C + i] = o; o += d[2];
        shoff[3 * N_NODES_C + i] = o;
    }
}

// ---------------------------------------------------------------------------
// CSR fill — separate kernel, atomic-free. 4 edges/thread, no LDS -> high
// occupancy to hide the random shoff read + src scatter latency. Runs BEFORE
// qcalc so its scatter traffic doesn't interfere with the W3T slice loop.
// ---------------------------------------------------------------------------
__global__ void fill_kernel(const int* __restrict__ row,
                            const int* __restrict__ col,
                            const int* __restrict__ shoff,
                            const int* __restrict__ rank,
                            int* __restrict__ src)
{
    const int base = blockIdx.x * 1024 + threadIdx.x;
    #pragma unroll
    for (int u = 0; u < 4; ++u) {
        const int e = base + u * 256;
        if (e < N_EDGES_C) {
            const int c = col[e];
            const int kk = (e >> 8) & 3;
            const int slot = shoff[kk * N_NODES_C + c] + rank[e];
            src[slot] = row[e];
        }
    }
}

// ---------------------------------------------------------------------------
// QCALC kernel (R1-exact structure, fill split out).
//  64 nodes/block, 4 waves x 16 nodes.
//  Phase 1: per-wave MLP (wave-private hb LDS, zero barriers).
//  Phase 2: qcalc over all 32 y (double-buffered swizzled W3T slices in
//  shared LDS); h B-frags from the wave's own hb. Stores qa*dinv.
// ---------------------------------------------------------------------------
__launch_bounds__(256, 4)
__global__ void qcalc_kernel(const float* __restrict__ xf,
                             const float* __restrict__ b_in,
                             const float* __restrict__ b_mid,
                             const _Float16* __restrict__ wT,
                             const _Float16* __restrict__ W3T,
                             const float* __restrict__ b_out,
                             const float* __restrict__ dinv,
                             float* __restrict__ qs)
{
    __shared__ _Float16 hball[4][16 * XSTR];   // 4 x 2304 B = 9216 B
    __shared__ _Float16 ws3[2][4096];          // 16384 B

    const int t    = threadIdx.x;
    const int w    = t >> 6;
    const int lane = t & 63;
    const int quad = lane >> 4;
    const int lrow = lane & 15;
    const int node0 = blockIdx.x * 64 + w * 16;
    _Float16* hb = hball[w];

    // ---- phase 1a: stage x -> f16 hb ----
    {
        const int n = min(node0 + lrow, N_NODES_C - 1);
        const float4* src4 = (const float4*)(xf + (size_t)n * 64 + quad * 16);
        _Float16 tmp[16];
        #pragma unroll
        for (int i = 0; i < 4; ++i) {
            const float4 v = src4[i];
            tmp[i * 4 + 0] = (_Float16)v.x;
            tmp[i * 4 + 1] = (_Float16)v.y;
            tmp[i * 4 + 2] = (_Float16)v.z;
            tmp[i * 4 + 3] = (_Float16)v.w;
        }
        *(f16x8*)&hb[lrow * XSTR + quad * 16]     = *(f16x8*)&tmp[0];
        *(f16x8*)&hb[lrow * XSTR + quad * 16 + 8] = *(f16x8*)&tmp[8];
    }

    // ---- phase 1b: 7 layers, wave-private, 16 nodes/wave ----
    {
        const _Float16* wTl = wT;
        const float* bsrc = b_in;
        for (int l = 0; l < 7; ++l) {
            const f16x8 A0 = *(const f16x8*)&hb[lrow * XSTR + quad * 8];
            const f16x8 A1 = *(const f16x8*)&hb[lrow * XSTR + 32 + quad * 8];
            #pragma unroll
            for (int Nt = 0; Nt < 4; ++Nt) {
                const f16x8 B0 = *(const f16x8*)(wTl + (Nt * 16 + lrow) * 64 + quad * 8);
                const f16x8 B1 = *(const f16x8*)(wTl + (Nt * 16 + lrow) * 64 + 32 + quad * 8);
                const float bias = bsrc[Nt * 16 + lrow];
                f32x4 C = {0.f, 0.f, 0.f, 0.f};
                C = __builtin_amdgcn_mfma_f32_16x16x32_f16(A0, B0, C, 0, 0, 0);
                C = __builtin_amdgcn_mfma_f32_16x16x32_f16(A1, B1, C, 0, 0, 0);
                #pragma unroll
                for (int r = 0; r < 4; ++r) {
                    const float v = fmaxf(C[r] + bias, 0.f);
                    hb[(quad * 4 + r) * XSTR + Nt * 16 + lrow] = (_Float16)v;
                }
            }
            wTl += 4096;
            bsrc = b_mid + (size_t)l * 64;
        }
    }

    // ---- phase 2 setup: B-frags (h) from wave-private LDS ----
    const int ra = node0 + lrow;
    const int na = min(ra, N_NODES_C - 1);

    f16x8 Bha[2];
    #pragma unroll
    for (int ks = 0; ks < 2; ++ks)
        Bha[ks] = *(const f16x8*)&hb[lrow * XSTR + ks * 32 + quad * 8];
    float4 xca[4];
    #pragma unroll
    for (int xt = 0; xt < 4; ++xt)
        xca[xt] = *(const float4*)(xf + (size_t)na * 64 + xt * 16 + quad * 4);
    const float dva = dinv[na];

    // prefetch slice y=0 (dense copy preserves the global-side swizzle)
    {
        const f16x8 v0 = *(const f16x8*)(W3T + (size_t)t * 8);
        const f16x8 v1 = *(const f16x8*)(W3T + (size_t)(t + 256) * 8);
        *(f16x8*)(&ws3[0][t * 8]) = v0;
        *(f16x8*)(&ws3[0][(t + 256) * 8]) = v1;
    }

    const int swz = lrow & 7;
    const int cp0 = ((quad)     ^ swz) * 8;   // ks=0 chunk offset (f16)
    const int cp1 = ((4 + quad) ^ swz) * 8;   // ks=1 chunk offset

    __syncthreads();

    // ---- phase 2: qcalc over all 32 y (double-buffered W3T slices) ----
    for (int y = 0; y < 32; ++y) {
        f16x8 nv0, nv1;
        if (y + 1 < 32) {
            nv0 = *(const f16x8*)(W3T + (size_t)(y + 1) * 4096 + t * 8);
            nv1 = *(const f16x8*)(W3T + (size_t)(y + 1) * 4096 + (t + 256) * 8);
        }

        const _Float16* cur = ws3[y & 1];
        float qa = 0.f;
        #pragma unroll
        for (int xt = 0; xt < 4; ++xt) {
            const _Float16* rp = cur + (xt * 16 + lrow) * 64;
            const f16x8 A0 = *(const f16x8*)(rp + cp0);
            const f16x8 A1 = *(const f16x8*)(rp + cp1);
            f32x4 Ca = {0.f, 0.f, 0.f, 0.f};
            Ca = __builtin_amdgcn_mfma_f32_16x16x32_f16(A0, Bha[0], Ca, 0, 0, 0);
            Ca = __builtin_amdgcn_mfma_f32_16x16x32_f16(A1, Bha[1], Ca, 0, 0, 0);

            const float4 bf = *(const float4*)(b_out + y * 64 + xt * 16 + quad * 4);
            qa += (Ca[0] + bf.x) * xca[xt].x + (Ca[1] + bf.y) * xca[xt].y
                + (Ca[2] + bf.z) * xca[xt].z + (Ca[3] + bf.w) * xca[xt].w;
        }
        qa += __shfl_xor(qa, 16);
        qa += __shfl_xor(qa, 32);

        if (quad == (y >> 3)) {               // quad q stores y in [8q, 8q+8)
            if (ra < N_NODES_C) qs[(size_t)ra * 32 + y] = qa * dva;
        }

        if (y + 1 < 32) {
            _Float16* nxt = ws3[(y + 1) & 1];
            *(f16x8*)(&nxt[t * 8]) = nv0;
            *(f16x8*)(&nxt[(t + 256) * 8]) = nv1;
        }
        __syncthreads();
    }
}

// ---------------------------------------------------------------------------
// Gather: out[n,y] = dinv[n] * sum_{s in CSR row n} qs[src[s], y]
// 8 threads/node, float4 per thread (32 nodes per 256-thread block).
// ---------------------------------------------------------------------------
__global__ void gather_kernel(const int* __restrict__ rowptr, const int* __restrict__ src,
                              const float* __restrict__ qs, const float* __restrict__ dinv,
                              float* __restrict__ out)
{
    const int t = threadIdx.x;
    const int node = blockIdx.x * 32 + (t >> 3);
    if (node >= N_NODES_C) return;
    const int yq = (t & 7) * 4;
    const int s0 = rowptr[node];
    const int s1 = rowptr[node + 1];
    float4 acc = {0.f, 0.f, 0.f, 0.f};
    int s = s0;
    for (; s + 4 <= s1; s += 4) {
        const int r0 = src[s], r1 = src[s + 1], r2 = src[s + 2], r3 = src[s + 3];
        const float4 a0 = *(const float4*)(qs + (size_t)r0 * 32 + yq);
        const float4 a1 = *(const float4*)(qs + (size_t)r1 * 32 + yq);
        const float4 a2 = *(const float4*)(qs + (size_t)r2 * 32 + yq);
        const float4 a3 = *(const float4*)(qs + (size_t)r3 * 32 + yq);
        acc.x += a0.x + a1.x + a2.x + a3.x;
        acc.y += a0.y + a1.y + a2.y + a3.y;
        acc.z += a0.z + a1.z + a2.z + a3.z;
        acc.w += a0.w + a1.w + a2.w + a3.w;
    }
    for (; s < s1; ++s) {
        const float4 a = *(const float4*)(qs + (size_t)src[s] * 32 + yq);
        acc.x += a.x; acc.y += a.y; acc.z += a.z; acc.w += a.w;
    }
    const float dv = dinv[node];
    float4 r;
    r.x = acc.x * dv; r.y = acc.y * dv; r.z = acc.z * dv; r.w = acc.w * dv;
    *(float4*)(out + (size_t)node * 32 + yq) = r;
}

// ---------------------------------------------------------------------------
extern "C" void kernel_launch(void* const* d_in, const int* in_sizes, int n_in,
                              void* d_out, int out_size, void* d_ws, size_t ws_size,
                              hipStream_t stream)
{
    const float* xf    = (const float*)d_in[0];
    const int*   eidx  = (const int*)d_in[1];
    const float* w_in  = (const float*)d_in[2];
    const float* b_in  = (const float*)d_in[3];
    const float* w_mid = (const float*)d_in[4];
    const float* b_mid = (const float*)d_in[5];
    const float* w_out = (const float*)d_in[6];
    const float* b_out = (const float*)d_in[7];
    float* out = (float*)d_out;

    const int* row = eidx;
    const int* col = eidx + N_EDGES_C;

    // workspace layout (bytes)
    char* ws = (char*)d_ws;
    float*    qs     = (float*)(ws + 0);             //  6,400,000
    int*      deg4   = (int*)(ws + 6400000);         //    800,000 (4 shadows)
    float*    dinv   = (float*)(ws + 7200000);       //    200,000
    _Float16* wT     = (_Float16*)(ws + 7400000);    //     57,344
    _Float16* W3T    = (_Float16*)(ws + 7457344);    //    262,144
    int*      rowptr = (int*)(ws + 7719488);         //    200,004
    int*      shoff  = (int*)(ws + 7919492);         //    800,000 (4 shadows)
    int*      rank   = (int*)(ws + 8719492);         //  3,200,000
    int*      srcb   = (int*)(ws + 11919492);        //  3,200,000
    int*      bsum   = (int*)(ws + 15119492);        //        784
    int*      boff   = (int*)(ws + 15120276);        //        784

    hipMemsetAsync(deg4, 0, 4 * N_NODES_C * sizeof(int), stream);

    prep_deg_kernel<<<dim3(624 + DEG_BLOCKS), dim3(256), 0, stream>>>(
        w_in, w_mid, w_out, col, wT, W3T, deg4, rank);

    scan1_kernel<<<dim3(196), dim3(256), 0, stream>>>(deg4, bsum);
    scan2_kernel<<<dim3(1), dim3(256), 0, stream>>>(bsum, boff, rowptr);
    scan3_kernel<<<dim3(196), dim3(256), 0, stream>>>(deg4, boff, rowptr, shoff, dinv);

    fill_kernel<<<dim3(FILL_BLOCKS), dim3(256), 0, stream>>>(row, col, shoff, rank, srcb);

    qcalc_kernel<<<dim3(MQ_BLOCKS), dim3(256), 0, stream>>>(
        xf, b_in, b_mid, wT, W3T, b_out, dinv, qs);

    gather_kernel<<<dim3(1563), dim3(256), 0, stream>>>(rowptr, srcb, qs, dinv, out);
}

// Round 6
// 207.286 us; speedup vs baseline: 1.0114x; 1.0114x over previous
//
#include <hip/hip_runtime.h>
#include <cstddef>

#define N_NODES_C 50000
#define N_EDGES_C 800000

typedef _Float16 f16x8 __attribute__((ext_vector_type(8)));
typedef float    f32x4 __attribute__((ext_vector_type(4)));

constexpr int XSTR = 72;           // f16 stride for per-wave h buffer
constexpr int MQ_BLOCKS   = 782;   // ceil(50000/64) compute blocks
constexpr int FILL_BLOCKS = 782;   // ceil(800000/1024), 4 edges/thread
constexpr int DEG_BLOCKS  = 782;   // ceil(800000/1024), 4 edges/thread

// ---------------------------------------------------------------------------
// prep (wT, W3T swizzled) + deg fused (4 shadow arrays, 4 edges/thread).
//  wT[l][j][k] = W_l[k][j] (f16)                      idx [0, 28672)
//  W3T[r=y*64+x][64 k] (f16), 16B chunks XOR-swizzled: chunk c of row r
//  stored at chunk c^(r&7). Value = w_out[k*2048 + r].   idx [28672, 159744)
//  COALESCED-READ mapping: consecutive threads read consecutive source
//  elements (j for w_in/w_mid, r for w_out); the transpose scatter is taken
//  on the WRITE side (stores are fire-and-forget).
//  Deg pass ALSO captures rank[e] = old count in shadow k = (e>>8)&3 —
//  this makes the CSR fill atomic-free (slot = shoff[k][col] + rank[e]).
// ---------------------------------------------------------------------------
__global__ void prep_deg_kernel(const float* __restrict__ w_in,
                                const float* __restrict__ w_mid,
                                const float* __restrict__ w_out,
                                const int* __restrict__ col,
                                _Float16* __restrict__ wT,
                                _Float16* __restrict__ W3T,
                                int* __restrict__ deg4,   // [4][N_NODES_C]
                                int* __restrict__ rank)   // [N_EDGES_C]
{
    const int b = blockIdx.x;
    if (b < 624) {
        const int idx = b * 256 + threadIdx.x;
        if (idx < 7 * 4096) {
            const int l = idx >> 12, rem = idx & 4095;
            const int k = rem >> 6, j = rem & 63;      // lanes: consecutive j
            const float v = (l == 0) ? w_in[k * 64 + j]
                                     : w_mid[(size_t)(l - 1) * 4096 + k * 64 + j];
            wT[(size_t)l * 4096 + j * 64 + k] = (_Float16)v;
        } else {
            const int i2 = idx - 7 * 4096;             // < 131072
            const int k = i2 >> 11, r = i2 & 2047;     // lanes: consecutive r
            const int c = k >> 3;
            const int pos = ((c ^ (r & 7)) << 3) | (k & 7);
            W3T[(size_t)r * 64 + pos] = (_Float16)w_out[(size_t)k * 2048 + r];
        }
    } else {
        const int e0 = (b - 624) * 1024 + threadIdx.x;
        #pragma unroll
        for (int k = 0; k < 4; ++k) {
            const int e = e0 + k * 256;
            if (e < N_EDGES_C)
                rank[e] = atomicAdd(&deg4[k * N_NODES_C + col[e]], 1);
        }
    }
}

// ---------------------------------------------------------------------------
// 3-phase parallel scan over deg = sum of 4 shadows; scan3 also emits dinv
// and the per-shadow exclusive offsets shoff[k][i] used by the fill.
// ---------------------------------------------------------------------------
__global__ void scan1_kernel(const int* __restrict__ deg4, int* __restrict__ bsum)
{
    const int t = threadIdx.x;
    const int i = blockIdx.x * 256 + t;
    int v = 0;
    if (i < N_NODES_C) {
        #pragma unroll
        for (int k = 0; k < 4; ++k) v += deg4[k * N_NODES_C + i];
    }
    #pragma unroll
    for (int d = 1; d < 64; d <<= 1) v += __shfl_xor(v, d);
    __shared__ int s[4];
    if ((t & 63) == 0) s[t >> 6] = v;
    __syncthreads();
    if (t == 0) bsum[blockIdx.x] = s[0] + s[1] + s[2] + s[3];
}

__global__ void scan2_kernel(const int* __restrict__ bsum, int* __restrict__ boff,
                             int* __restrict__ rowptr)
{
    __shared__ int sh[256];
    const int t = threadIdx.x;
    const int v = (t < 196) ? bsum[t] : 0;
    sh[t] = v;
    __syncthreads();
    for (int d = 1; d < 256; d <<= 1) {
        const int u = (t >= d) ? sh[t - d] : 0;
        __syncthreads();
        sh[t] += u;
        __syncthreads();
    }
    if (t < 196) boff[t] = sh[t] - v;     // exclusive
    if (t == 0) rowptr[N_NODES_C] = N_EDGES_C;
}

__global__ void scan3_kernel(const int* __restrict__ deg4, const int* __restrict__ boff,
                             int* __restrict__ rowptr, int* __restrict__ shoff,
                             float* __restrict__ dinv)
{
    const int t = threadIdx.x;
    const int i = blockIdx.x * 256 + t;
    const int lane = t & 63, w = t >> 6;
    int d[4];
    int v = 0;
    if (i < N_NODES_C) {
        #pragma unroll
        for (int k = 0; k < 4; ++k) { d[k] = deg4[k * N_NODES_C + i]; v += d[k]; }
    } else {
        d[0] = d[1] = d[2] = d[3] = 0;
    }
    int inc = v;
    #pragma unroll
    for (int dd = 1; dd < 64; dd <<= 1) {
        const int u = __shfl_up(inc, dd);
        if (lane >= dd) inc += u;
    }
    __shared__ int ws[4];
    if (lane == 63) ws[w] = inc;
    __syncthreads();
    int wo = 0;
    #pragma unroll
    for (int k = 0; k < 4; ++k) if (k < w) wo += ws[k];
    const int excl = boff[blockIdx.x] + wo + inc - v;
    if (i < N_NODES_C) {
        rowptr[i] = excl;
        dinv[i] = (v > 0) ? rsqrtf((float)v) : 0.f;
        int o = excl;
        shoff[0 * N_NODES_C + i] = o; o += d[0];
        shoff[1 * N_NODES_C + i] = o; o += d[1];
        shoff[2 * N_NODES_C + i] = o; o += d[2];
        shoff[3 * N_NODES_C + i] = o;
    }
}

// ---------------------------------------------------------------------------
// CSR fill — separate kernel, atomic-free. 4 edges/thread, no LDS.
// ---------------------------------------------------------------------------
__global__ void fill_kernel(const int* __restrict__ row,
                            const int* __restrict__ col,
                            const int* __restrict__ shoff,
                            const int* __restrict__ rank,
                            int* __restrict__ src)
{
    const int base = blockIdx.x * 1024 + threadIdx.x;
    #pragma unroll
    for (int u = 0; u < 4; ++u) {
        const int e = base + u * 256;
        if (e < N_EDGES_C) {
            const int c = col[e];
            const int kk = (e >> 8) & 3;
            const int slot = shoff[kk * N_NODES_C + c] + rank[e];
            src[slot] = row[e];
        }
    }
}

// ---------------------------------------------------------------------------
// QCALC kernel.  64 nodes/block, 4 waves x 16 nodes.
//  Phase 1: per-wave MLP (wave-private hb LDS, zero barriers).
//  Phase 2: qcalc over all 32 y, double-buffered swizzled W3T slices with a
//  2-DEEP register prefetch ring: iteration y issues loads for slice y+2;
//  slice y+1 (loaded last iteration, ~1.5 iterations of slack vs L2 latency)
//  is ds_written this iteration. The vmcnt wait before the ds_write now
//  targets loads issued a full iteration earlier.
// ---------------------------------------------------------------------------
__launch_bounds__(256, 4)
__global__ void qcalc_kernel(const float* __restrict__ xf,
                             const float* __restrict__ b_in,
                             const float* __restrict__ b_mid,
                             const _Float16* __restrict__ wT,
                             const _Float16* __restrict__ W3T,
                             const float* __restrict__ b_out,
                             const float* __restrict__ dinv,
                             float* __restrict__ qs)
{
    __shared__ _Float16 hball[4][16 * XSTR];   // 4 x 2304 B = 9216 B
    __shared__ _Float16 ws3[2][4096];          // 16384 B

    const int t    = threadIdx.x;
    const int w    = t >> 6;
    const int lane = t & 63;
    const int quad = lane >> 4;
    const int lrow = lane & 15;
    const int node0 = blockIdx.x * 64 + w * 16;
    _Float16* hb = hball[w];

    // ---- phase 1a: stage x -> f16 hb ----
    {
        const int n = min(node0 + lrow, N_NODES_C - 1);
        const float4* src4 = (const float4*)(xf + (size_t)n * 64 + quad * 16);
        _Float16 tmp[16];
        #pragma unroll
        for (int i = 0; i < 4; ++i) {
            const float4 v = src4[i];
            tmp[i * 4 + 0] = (_Float16)v.x;
            tmp[i * 4 + 1] = (_Float16)v.y;
            tmp[i * 4 + 2] = (_Float16)v.z;
            tmp[i * 4 + 3] = (_Float16)v.w;
        }
        *(f16x8*)&hb[lrow * XSTR + quad * 16]     = *(f16x8*)&tmp[0];
        *(f16x8*)&hb[lrow * XSTR + quad * 16 + 8] = *(f16x8*)&tmp[8];
    }

    // ---- phase 1b: 7 layers, wave-private, 16 nodes/wave ----
    {
        const _Float16* wTl = wT;
        const float* bsrc = b_in;
        for (int l = 0; l < 7; ++l) {
            const f16x8 A0 = *(const f16x8*)&hb[lrow * XSTR + quad * 8];
            const f16x8 A1 = *(const f16x8*)&hb[lrow * XSTR + 32 + quad * 8];
            #pragma unroll
            for (int Nt = 0; Nt < 4; ++Nt) {
                const f16x8 B0 = *(const f16x8*)(wTl + (Nt * 16 + lrow) * 64 + quad * 8);
                const f16x8 B1 = *(const f16x8*)(wTl + (Nt * 16 + lrow) * 64 + 32 + quad * 8);
                const float bias = bsrc[Nt * 16 + lrow];
                f32x4 C = {0.f, 0.f, 0.f, 0.f};
                C = __builtin_amdgcn_mfma_f32_16x16x32_f16(A0, B0, C, 0, 0, 0);
                C = __builtin_amdgcn_mfma_f32_16x16x32_f16(A1, B1, C, 0, 0, 0);
                #pragma unroll
                for (int r = 0; r < 4; ++r) {
                    const float v = fmaxf(C[r] + bias, 0.f);
                    hb[(quad * 4 + r) * XSTR + Nt * 16 + lrow] = (_Float16)v;
                }
            }
            wTl += 4096;
            bsrc = b_mid + (size_t)l * 64;
        }
    }

    // ---- phase 2 setup: B-frags (h) from wave-private LDS ----
    const int ra = node0 + lrow;
    const int na = min(ra, N_NODES_C - 1);

    f16x8 Bha[2];
    #pragma unroll
    for (int ks = 0; ks < 2; ++ks)
        Bha[ks] = *(const f16x8*)&hb[lrow * XSTR + ks * 32 + quad * 8];
    float4 xca[4];
    #pragma unroll
    for (int xt = 0; xt < 4; ++xt)
        xca[xt] = *(const float4*)(xf + (size_t)na * 64 + xt * 16 + quad * 4);
    const float dva = dinv[na];

    // slice 0 -> LDS buf0; slice 1 -> prefetch regs (pvA)
    f16x8 pvA0, pvA1;
    {
        const f16x8 v0 = *(const f16x8*)(W3T + (size_t)t * 8);
        const f16x8 v1 = *(const f16x8*)(W3T + (size_t)(t + 256) * 8);
        *(f16x8*)(&ws3[0][t * 8]) = v0;
        *(f16x8*)(&ws3[0][(t + 256) * 8]) = v1;
        pvA0 = *(const f16x8*)(W3T + 4096 + (size_t)t * 8);
        pvA1 = *(const f16x8*)(W3T + 4096 + (size_t)(t + 256) * 8);
    }

    const int swz = lrow & 7;
    const int cp0 = ((quad)     ^ swz) * 8;   // ks=0 chunk offset (f16)
    const int cp1 = ((4 + quad) ^ swz) * 8;   // ks=1 chunk offset

    __syncthreads();

    // ---- phase 2: qcalc over all 32 y (2-deep prefetch ring) ----
    for (int y = 0; y < 32; ++y) {
        f16x8 pvB0 = pvA0, pvB1 = pvA1;       // default keeps regs defined
        if (y + 2 < 32) {
            pvB0 = *(const f16x8*)(W3T + (size_t)(y + 2) * 4096 + t * 8);
            pvB1 = *(const f16x8*)(W3T + (size_t)(y + 2) * 4096 + (t + 256) * 8);
        }

        const _Float16* cur = ws3[y & 1];
        float qa = 0.f;
        #pragma unroll
        for (int xt = 0; xt < 4; ++xt) {
            const _Float16* rp = cur + (xt * 16 + lrow) * 64;
            const f16x8 A0 = *(const f16x8*)(rp + cp0);
            const f16x8 A1 = *(const f16x8*)(rp + cp1);
            f32x4 Ca = {0.f, 0.f, 0.f, 0.f};
            Ca = __builtin_amdgcn_mfma_f32_16x16x32_f16(A0, Bha[0], Ca, 0, 0, 0);
            Ca = __builtin_amdgcn_mfma_f32_16x16x32_f16(A1, Bha[1], Ca, 0, 0, 0);

            const float4 bf = *(const float4*)(b_out + y * 64 + xt * 16 + quad * 4);
            qa += (Ca[0] + bf.x) * xca[xt].x + (Ca[1] + bf.y) * xca[xt].y
                + (Ca[2] + bf.z) * xca[xt].z + (Ca[3] + bf.w) * xca[xt].w;
        }
        qa += __shfl_xor(qa, 16);
        qa += __shfl_xor(qa, 32);

        if (quad == (y >> 3)) {               // quad q stores y in [8q, 8q+8)
            if (ra < N_NODES_C) qs[(size_t)ra * 32 + y] = qa * dva;
        }

        if (y + 1 < 32) {                     // write slice y+1 (loaded 1 iter ago)
            _Float16* nxt = ws3[(y + 1) & 1];
            *(f16x8*)(&nxt[t * 8]) = pvA0;
            *(f16x8*)(&nxt[(t + 256) * 8]) = pvA1;
        }
        __syncthreads();
        pvA0 = pvB0; pvA1 = pvB1;
    }
}

// ---------------------------------------------------------------------------
// Gather: out[n,y] = dinv[n] * sum_{s in CSR row n} qs[src[s], y]
// 8 threads/node, float4 per thread (32 nodes per 256-thread block).
// ---------------------------------------------------------------------------
__global__ void gather_kernel(const int* __restrict__ rowptr, const int* __restrict__ src,
                              const float* __restrict__ qs, const float* __restrict__ dinv,
                              float* __restrict__ out)
{
    const int t = threadIdx.x;
    const int node = blockIdx.x * 32 + (t >> 3);
    if (node >= N_NODES_C) return;
    const int yq = (t & 7) * 4;
    const int s0 = rowptr[node];
    const int s1 = rowptr[node + 1];
    float4 acc = {0.f, 0.f, 0.f, 0.f};
    int s = s0;
    for (; s + 4 <= s1; s += 4) {
        const int r0 = src[s], r1 = src[s + 1], r2 = src[s + 2], r3 = src[s + 3];
        const float4 a0 = *(const float4*)(qs + (size_t)r0 * 32 + yq);
        const float4 a1 = *(const float4*)(qs + (size_t)r1 * 32 + yq);
        const float4 a2 = *(const float4*)(qs + (size_t)r2 * 32 + yq);
        const float4 a3 = *(const float4*)(qs + (size_t)r3 * 32 + yq);
        acc.x += a0.x + a1.x + a2.x + a3.x;
        acc.y += a0.y + a1.y + a2.y + a3.y;
        acc.z += a0.z + a1.z + a2.z + a3.z;
        acc.w += a0.w + a1.w + a2.w + a3.w;
    }
    for (; s < s1; ++s) {
        const float4 a = *(const float4*)(qs + (size_t)src[s] * 32 + yq);
        acc.x += a.x; acc.y += a.y; acc.z += a.z; acc.w += a.w;
    }
    const float dv = dinv[node];
    float4 r;
    r.x = acc.x * dv; r.y = acc.y * dv; r.z = acc.z * dv; r.w = acc.w * dv;
    *(float4*)(out + (size_t)node * 32 + yq) = r;
}

// ---------------------------------------------------------------------------
extern "C" void kernel_launch(void* const* d_in, const int* in_sizes, int n_in,
                              void* d_out, int out_size, void* d_ws, size_t ws_size,
                              hipStream_t stream)
{
    const float* xf    = (const float*)d_in[0];
    const int*   eidx  = (const int*)d_in[1];
    const float* w_in  = (const float*)d_in[2];
    const float* b_in  = (const float*)d_in[3];
    const float* w_mid = (const float*)d_in[4];
    const float* b_mid = (const float*)d_in[5];
    const float* w_out = (const float*)d_in[6];
    const float* b_out = (const float*)d_in[7];
    float* out = (float*)d_out;

    const int* row = eidx;
    const int* col = eidx + N_EDGES_C;

    // workspace layout (bytes)
    char* ws = (char*)d_ws;
    float*    qs     = (float*)(ws + 0);             //  6,400,000
    int*      deg4   = (int*)(ws + 6400000);         //    800,000 (4 shadows)
    float*    dinv   = (float*)(ws + 7200000);       //    200,000
    _Float16* wT     = (_Float16*)(ws + 7400000);    //     57,344
    _Float16* W3T    = (_Float16*)(ws + 7457344);    //    262,144
    int*      rowptr = (int*)(ws + 7719488);         //    200,004
    int*      shoff  = (int*)(ws + 7919492);         //    800,000 (4 shadows)
    int*      rank   = (int*)(ws + 8719492);         //  3,200,000
    int*      srcb   = (int*)(ws + 11919492);        //  3,200,000
    int*      bsum   = (int*)(ws + 15119492);        //        784
    int*      boff   = (int*)(ws + 15120276);        //        784

    hipMemsetAsync(deg4, 0, 4 * N_NODES_C * sizeof(int), stream);

    prep_deg_kernel<<<dim3(624 + DEG_BLOCKS), dim3(256), 0, stream>>>(
        w_in, w_mid, w_out, col, wT, W3T, deg4, rank);

    scan1_kernel<<<dim3(196), dim3(256), 0, stream>>>(deg4, bsum);
    scan2_kernel<<<dim3(1), dim3(256), 0, stream>>>(bsum, boff, rowptr);
    scan3_kernel<<<dim3(196), dim3(256), 0, stream>>>(deg4, boff, rowptr, shoff, dinv);

    fill_kernel<<<dim3(FILL_BLOCKS), dim3(256), 0, stream>>>(row, col, shoff, rank, srcb);

    qcalc_kernel<<<dim3(MQ_BLOCKS), dim3(256), 0, stream>>>(
        xf, b_in, b_mid, wT, W3T, b_out, dinv, qs);

    gather_kernel<<<dim3(1563), dim3(256), 0, stream>>>(rowptr, srcb, qs, dinv, out);
}

// Round 7
// 189.937 us; speedup vs baseline: 1.1038x; 1.0913x over previous
//
#include <hip/hip_runtime.h>
#include <cstddef>

#define N_NODES_C 50000
#define N_NODES_PAD 50048
#define N_EDGES_C 800000

typedef _Float16 f16x8 __attribute__((ext_vector_type(8)));
typedef float    f32x4 __attribute__((ext_vector_type(4)));

constexpr int XSTR = 72;           // f16 stride for per-wave h buffer
constexpr int MQ_BLOCKS   = 782;   // ceil(50000/64) compute blocks
constexpr int FILL_BLOCKS = 782;   // ceil(800000/1024), 4 edges/thread
constexpr int DEG_BLOCKS  = 782;   // ceil(800000/1024), 4 edges/thread

// global -> LDS direct copy, 16B per lane. lds ptr must be wave-uniform base;
// HW writes base + lane*16. global ptr is per-lane.
__device__ __forceinline__ void gll16(const void* g, void* l) {
    __builtin_amdgcn_global_load_lds(
        (const __attribute__((address_space(1))) void*)g,
        (__attribute__((address_space(3))) void*)l, 16, 0, 0);
}

// ---------------------------------------------------------------------------
// prep (wT, W3T swizzled) + deg fused (4 shadow arrays, 4 edges/thread).
//  wT[l][j][k] = W_l[k][j] (f16)                      idx [0, 28672)
//  W3T[r=y*64+x][64 k] (f16), 16B chunks XOR-swizzled: chunk c of row r
//  stored at chunk c^(r&7). Value = w_out[k*2048 + r].
//  Coalesced-read mapping (transpose scatter on the write side).
//  Deg pass captures rank[e] = old count in shadow k = (e>>8)&3 —
//  makes the CSR fill atomic-free (slot = shoff[k][col] + rank[e]).
// ---------------------------------------------------------------------------
__global__ void prep_deg_kernel(const float* __restrict__ w_in,
                                const float* __restrict__ w_mid,
                                const float* __restrict__ w_out,
                                const int* __restrict__ col,
                                _Float16* __restrict__ wT,
                                _Float16* __restrict__ W3T,
                                int* __restrict__ deg4,   // [4][N_NODES_C]
                                int* __restrict__ rank)   // [N_EDGES_C]
{
    const int b = blockIdx.x;
    if (b < 624) {
        const int idx = b * 256 + threadIdx.x;
        if (idx < 7 * 4096) {
            const int l = idx >> 12, rem = idx & 4095;
            const int k = rem >> 6, j = rem & 63;      // lanes: consecutive j
            const float v = (l == 0) ? w_in[k * 64 + j]
                                     : w_mid[(size_t)(l - 1) * 4096 + k * 64 + j];
            wT[(size_t)l * 4096 + j * 64 + k] = (_Float16)v;
        } else {
            const int i2 = idx - 7 * 4096;             // < 131072
            const int k = i2 >> 11, r = i2 & 2047;     // lanes: consecutive r
            const int c = k >> 3;
            const int pos = ((c ^ (r & 7)) << 3) | (k & 7);
            W3T[(size_t)r * 64 + pos] = (_Float16)w_out[(size_t)k * 2048 + r];
        }
    } else {
        const int e0 = (b - 624) * 1024 + threadIdx.x;
        #pragma unroll
        for (int k = 0; k < 4; ++k) {
            const int e = e0 + k * 256;
            if (e < N_EDGES_C)
                rank[e] = atomicAdd(&deg4[k * N_NODES_C + col[e]], 1);
        }
    }
}

// ---------------------------------------------------------------------------
// 3-phase parallel scan; scan3 also emits dinv and per-shadow offsets shoff.
// ---------------------------------------------------------------------------
__global__ void scan1_kernel(const int* __restrict__ deg4, int* __restrict__ bsum)
{
    const int t = threadIdx.x;
    const int i = blockIdx.x * 256 + t;
    int v = 0;
    if (i < N_NODES_C) {
        #pragma unroll
        for (int k = 0; k < 4; ++k) v += deg4[k * N_NODES_C + i];
    }
    #pragma unroll
    for (int d = 1; d < 64; d <<= 1) v += __shfl_xor(v, d);
    __shared__ int s[4];
    if ((t & 63) == 0) s[t >> 6] = v;
    __syncthreads();
    if (t == 0) bsum[blockIdx.x] = s[0] + s[1] + s[2] + s[3];
}

__global__ void scan2_kernel(const int* __restrict__ bsum, int* __restrict__ boff,
                             int* __restrict__ rowptr)
{
    __shared__ int sh[256];
    const int t = threadIdx.x;
    const int v = (t < 196) ? bsum[t] : 0;
    sh[t] = v;
    __syncthreads();
    for (int d = 1; d < 256; d <<= 1) {
        const int u = (t >= d) ? sh[t - d] : 0;
        __syncthreads();
        sh[t] += u;
        __syncthreads();
    }
    if (t < 196) boff[t] = sh[t] - v;     // exclusive
    if (t == 0) rowptr[N_NODES_C] = N_EDGES_C;
}

__global__ void scan3_kernel(const int* __restrict__ deg4, const int* __restrict__ boff,
                             int* __restrict__ rowptr, int* __restrict__ shoff,
                             float* __restrict__ dinv)
{
    const int t = threadIdx.x;
    const int i = blockIdx.x * 256 + t;
    const int lane = t & 63, w = t >> 6;
    int d[4];
    int v = 0;
    if (i < N_NODES_C) {
        #pragma unroll
        for (int k = 0; k < 4; ++k) { d[k] = deg4[k * N_NODES_C + i]; v += d[k]; }
    } else {
        d[0] = d[1] = d[2] = d[3] = 0;
    }
    int inc = v;
    #pragma unroll
    for (int dd = 1; dd < 64; dd <<= 1) {
        const int u = __shfl_up(inc, dd);
        if (lane >= dd) inc += u;
    }
    __shared__ int ws[4];
    if (lane == 63) ws[w] = inc;
    __syncthreads();
    int wo = 0;
    #pragma unroll
    for (int k = 0; k < 4; ++k) if (k < w) wo += ws[k];
    const int excl = boff[blockIdx.x] + wo + inc - v;
    if (i < N_NODES_C) {
        rowptr[i] = excl;
        dinv[i] = (v > 0) ? rsqrtf((float)v) : 0.f;
        int o = excl;
        shoff[0 * N_NODES_C + i] = o; o += d[0];
        shoff[1 * N_NODES_C + i] = o; o += d[1];
        shoff[2 * N_NODES_C + i] = o; o += d[2];
        shoff[3 * N_NODES_C + i] = o;
    }
}

// ---------------------------------------------------------------------------
// MEGA kernel: compute blocks first, fill blocks after (R1-proven overlap).
//  Compute blocks: 64 nodes, 4 waves x 16 nodes.
//   Phase 1: per-wave MLP (wave-private hb LDS region, zero barriers).
//   Phase 2: counted-vmcnt pipeline (T3/T4):
//     - 3-slice LDS ring fed by global_load_lds (linear dest; W3T is
//       pre-swizzled on the global side, so linear copy preserves swizzle).
//     - raw s_barrier (no implicit vmcnt drain) + asm s_waitcnt vmcnt(N).
//     - per iter exactly 2 gll + 1 store count against vmcnt; b_out lives in
//       LDS (overlays dead hball region) so no other vmem loads in the loop.
//     - qs store is unconditional-issue (qs padded to 50048 rows) so every
//       wave's vmcnt ledger is identical.
//   Ring ledger: iter y = [wait vmcnt | barrier | issue gll(y+2) into
//   ring[(y+2)%3] (== ring[(y-1)%3], all waves done with it per barrier) |
//   compute from ring[y%3] | store qs(y)].  Slice y's gll was issued at
//   iter y-2: ops newer than it at the wait = store(y-2) + 2 gll(y+1) +
//   store(y-1) = 4 -> vmcnt(4) steady; vmcnt(2)/(3) for y=0/1 (prologue
//   issued bout + slices 0,1).
// ---------------------------------------------------------------------------
__launch_bounds__(256, 4)
__global__ void mega_kernel(const float* __restrict__ xf,
                            const float* __restrict__ b_in,
                            const float* __restrict__ b_mid,
                            const _Float16* __restrict__ wT,
                            const _Float16* __restrict__ W3T,
                            const float* __restrict__ b_out,
                            const float* __restrict__ dinv,
                            float* __restrict__ qs,
                            const int* __restrict__ row,
                            const int* __restrict__ col,
                            const int* __restrict__ shoff,
                            const int* __restrict__ rank,
                            int* __restrict__ src)
{
    // 33792 B total: f16[0,4608) = hball (phase1) / b_out f32 (phase2);
    //                f16[4608,16896) = 3 x 4096 f16 slice ring.
    __shared__ _Float16 smem[16896];

    if (blockIdx.x >= MQ_BLOCKS) {
        // ---------------- fill part (no atomics) ----------------
        const int base = (blockIdx.x - MQ_BLOCKS) * 1024 + threadIdx.x;
        #pragma unroll
        for (int u = 0; u < 4; ++u) {
            const int e = base + u * 256;
            if (e < N_EDGES_C) {
                const int c = col[e];
                const int kk = (e >> 8) & 3;
                const int slot = shoff[kk * N_NODES_C + c] + rank[e];
                src[slot] = row[e];
            }
        }
        return;
    }

    const int t    = threadIdx.x;
    const int w    = t >> 6;
    const int lane = t & 63;
    const int quad = lane >> 4;
    const int lrow = lane & 15;
    const int node0 = blockIdx.x * 64 + w * 16;
    _Float16* hb = &smem[w * 16 * XSTR];

    // ---- phase 1a: stage x -> f16 hb ----
    {
        const int n = min(node0 + lrow, N_NODES_C - 1);
        const float4* src4 = (const float4*)(xf + (size_t)n * 64 + quad * 16);
        _Float16 tmp[16];
        #pragma unroll
        for (int i = 0; i < 4; ++i) {
            const float4 v = src4[i];
            tmp[i * 4 + 0] = (_Float16)v.x;
            tmp[i * 4 + 1] = (_Float16)v.y;
            tmp[i * 4 + 2] = (_Float16)v.z;
            tmp[i * 4 + 3] = (_Float16)v.w;
        }
        *(f16x8*)&hb[lrow * XSTR + quad * 16]     = *(f16x8*)&tmp[0];
        *(f16x8*)&hb[lrow * XSTR + quad * 16 + 8] = *(f16x8*)&tmp[8];
    }

    // ---- phase 1b: 7 layers, wave-private, 16 nodes/wave ----
    {
        const _Float16* wTl = wT;
        const float* bsrc = b_in;
        for (int l = 0; l < 7; ++l) {
            const f16x8 A0 = *(const f16x8*)&hb[lrow * XSTR + quad * 8];
            const f16x8 A1 = *(const f16x8*)&hb[lrow * XSTR + 32 + quad * 8];
            #pragma unroll
            for (int Nt = 0; Nt < 4; ++Nt) {
                const f16x8 B0 = *(const f16x8*)(wTl + (Nt * 16 + lrow) * 64 + quad * 8);
                const f16x8 B1 = *(const f16x8*)(wTl + (Nt * 16 + lrow) * 64 + 32 + quad * 8);
                const float bias = bsrc[Nt * 16 + lrow];
                f32x4 C = {0.f, 0.f, 0.f, 0.f};
                C = __builtin_amdgcn_mfma_f32_16x16x32_f16(A0, B0, C, 0, 0, 0);
                C = __builtin_amdgcn_mfma_f32_16x16x32_f16(A1, B1, C, 0, 0, 0);
                #pragma unroll
                for (int r = 0; r < 4; ++r) {
                    const float v = fmaxf(C[r] + bias, 0.f);
                    hb[(quad * 4 + r) * XSTR + Nt * 16 + lrow] = (_Float16)v;
                }
            }
            wTl += 4096;
            bsrc = b_mid + (size_t)l * 64;
        }
    }

    // ---- phase 2 setup: B-frags (h) from wave-private LDS ----
    const int ra = node0 + lrow;                 // < N_NODES_PAD always
    const int na = min(ra, N_NODES_C - 1);

    f16x8 Bha[2];
    #pragma unroll
    for (int ks = 0; ks < 2; ++ks)
        Bha[ks] = *(const f16x8*)&hb[lrow * XSTR + ks * 32 + quad * 8];
    float4 xca[4];
    #pragma unroll
    for (int xt = 0; xt < 4; ++xt)
        xca[xt] = *(const float4*)(xf + (size_t)na * 64 + xt * 16 + quad * 4);
    const float dva = dinv[na];

    // hball dead from here; __syncthreads drains vmcnt to 0 (clean ledger).
    __syncthreads();

    // ---- prologue: stage b_out (f32, 8KB) over hball region; slices 0,1 ----
    {
        float* lb = (float*)smem;                         // f32 view of [0,8192)B
        const float* gb = b_out + (size_t)(w * 64 + lane) * 4;
        gll16(gb,        lb + w * 256);                   // bytes [0,4096)
        gll16(gb + 1024, lb + 1024 + w * 256);            // bytes [4096,8192)
        #pragma unroll
        for (int s = 0; s < 2; ++s) {
            _Float16* ld = &smem[4608 + s * 4096 + w * 512];
            const _Float16* gs = W3T + (size_t)s * 4096 + (size_t)(w * 64 + lane) * 8;
            gll16(gs,        ld);                         // slice bytes [0,4096)
            gll16(gs + 2048, ld + 2048);                  // slice bytes [4096,8192)
        }
    }

    const int swz = lrow & 7;
    const int cp0 = ((quad)     ^ swz) * 8;   // ks=0 chunk offset (f16)
    const int cp1 = ((4 + quad) ^ swz) * 8;   // ks=1 chunk offset
    const float* lbf = (const float*)smem;    // staged b_out

    // ---- phase 2: counted-vmcnt 3-slice ring, one raw barrier per y ----
    int rcur = 0;                              // y % 3
    for (int y = 0; y < 32; ++y) {
        if (y == 0)      asm volatile("s_waitcnt vmcnt(2)" ::: "memory");
        else if (y == 1) asm volatile("s_waitcnt vmcnt(3)" ::: "memory");
        else             asm volatile("s_waitcnt vmcnt(4)" ::: "memory");
        __builtin_amdgcn_s_barrier();
        __builtin_amdgcn_sched_barrier(0);

        // issue slice (y+2)&31 into ring[(y+2)%3] (= ring[(y-1)%3], retired)
        {
            const int ys = (y + 2) & 31;
            const int ri = (rcur == 0) ? 2 : rcur - 1;
            _Float16* ld = &smem[4608 + ri * 4096 + w * 512];
            const _Float16* gs = W3T + (size_t)ys * 4096 + (size_t)(w * 64 + lane) * 8;
            gll16(gs,        ld);
            gll16(gs + 2048, ld + 2048);
        }

        const _Float16* cur = &smem[4608 + rcur * 4096];
        float qa = 0.f;
        #pragma unroll
        for (int xt = 0; xt < 4; ++xt) {
            const _Float16* rp = cur + (xt * 16 + lrow) * 64;
            const f16x8 A0 = *(const f16x8*)(rp + cp0);
            const f16x8 A1 = *(const f16x8*)(rp + cp1);
            f32x4 Ca = {0.f, 0.f, 0.f, 0.f};
            Ca = __builtin_amdgcn_mfma_f32_16x16x32_f16(A0, Bha[0], Ca, 0, 0, 0);
            Ca = __builtin_amdgcn_mfma_f32_16x16x32_f16(A1, Bha[1], Ca, 0, 0, 0);

            const float4 bf = *(const float4*)(lbf + y * 64 + xt * 16 + quad * 4);
            qa += (Ca[0] + bf.x) * xca[xt].x + (Ca[1] + bf.y) * xca[xt].y
                + (Ca[2] + bf.z) * xca[xt].z + (Ca[3] + bf.w) * xca[xt].w;
        }
        qa += __shfl_xor(qa, 16);
        qa += __shfl_xor(qa, 32);

        if (quad == (y >> 3)) {               // 16 lanes/wave always -> exec!=0
            qs[(size_t)ra * 32 + y] = qa * dva;   // qs padded to 50048 rows
        }

        rcur = (rcur == 2) ? 0 : rcur + 1;
    }
}

// ---------------------------------------------------------------------------
// Gather: out[n,y] = dinv[n] * sum_{s in CSR row n} qs[src[s], y]
// 8 threads/node, float4 per thread (32 nodes per 256-thread block).
// ---------------------------------------------------------------------------
__global__ void gather_kernel(const int* __restrict__ rowptr, const int* __restrict__ src,
                              const float* __restrict__ qs, const float* __restrict__ dinv,
                              float* __restrict__ out)
{
    const int t = threadIdx.x;
    const int node = blockIdx.x * 32 + (t >> 3);
    if (node >= N_NODES_C) return;
    const int yq = (t & 7) * 4;
    const int s0 = rowptr[node];
    const int s1 = rowptr[node + 1];
    float4 acc = {0.f, 0.f, 0.f, 0.f};
    int s = s0;
    for (; s + 4 <= s1; s += 4) {
        const int r0 = src[s], r1 = src[s + 1], r2 = src[s + 2], r3 = src[s + 3];
        const float4 a0 = *(const float4*)(qs + (size_t)r0 * 32 + yq);
        const float4 a1 = *(const float4*)(qs + (size_t)r1 * 32 + yq);
        const float4 a2 = *(const float4*)(qs + (size_t)r2 * 32 + yq);
        const float4 a3 = *(const float4*)(qs + (size_t)r3 * 32 + yq);
        acc.x += a0.x + a1.x + a2.x + a3.x;
        acc.y += a0.y + a1.y + a2.y + a3.y;
        acc.z += a0.z + a1.z + a2.z + a3.z;
        acc.w += a0.w + a1.w + a2.w + a3.w;
    }
    for (; s < s1; ++s) {
        const float4 a = *(const float4*)(qs + (size_t)src[s] * 32 + yq);
        acc.x += a.x; acc.y += a.y; acc.z += a.z; acc.w += a.w;
    }
    const float dv = dinv[node];
    float4 r;
    r.x = acc.x * dv; r.y = acc.y * dv; r.z = acc.z * dv; r.w = acc.w * dv;
    *(float4*)(out + (size_t)node * 32 + yq) = r;
}

// ---------------------------------------------------------------------------
extern "C" void kernel_launch(void* const* d_in, const int* in_sizes, int n_in,
                              void* d_out, int out_size, void* d_ws, size_t ws_size,
                              hipStream_t stream)
{
    const float* xf    = (const float*)d_in[0];
    const int*   eidx  = (const int*)d_in[1];
    const float* w_in  = (const float*)d_in[2];
    const float* b_in  = (const float*)d_in[3];
    const float* w_mid = (const float*)d_in[4];
    const float* b_mid = (const float*)d_in[5];
    const float* w_out = (const float*)d_in[6];
    const float* b_out = (const float*)d_in[7];
    float* out = (float*)d_out;

    const int* row = eidx;
    const int* col = eidx + N_EDGES_C;

    // workspace layout (bytes)
    char* ws = (char*)d_ws;
    float*    qs     = (float*)(ws + 0);             //  6,406,144 (50048 rows)
    int*      deg4   = (int*)(ws + 6406144);         //    800,000 (4 shadows)
    float*    dinv   = (float*)(ws + 7206144);       //    200,000
    _Float16* wT     = (_Float16*)(ws + 7406144);    //     57,344
    _Float16* W3T    = (_Float16*)(ws + 7463488);    //    262,144
    int*      rowptr = (int*)(ws + 7725632);         //    200,004
    int*      shoff  = (int*)(ws + 7925636);         //    800,000 (4 shadows)
    int*      rank   = (int*)(ws + 8725636);         //  3,200,000
    int*      srcb   = (int*)(ws + 11925636);        //  3,200,000
    int*      bsum   = (int*)(ws + 15125636);        //        784
    int*      boff   = (int*)(ws + 15126420);        //        784

    hipMemsetAsync(deg4, 0, 4 * N_NODES_C * sizeof(int), stream);

    prep_deg_kernel<<<dim3(624 + DEG_BLOCKS), dim3(256), 0, stream>>>(
        w_in, w_mid, w_out, col, wT, W3T, deg4, rank);

    scan1_kernel<<<dim3(196), dim3(256), 0, stream>>>(deg4, bsum);
    scan2_kernel<<<dim3(1), dim3(256), 0, stream>>>(bsum, boff, rowptr);
    scan3_kernel<<<dim3(196), dim3(256), 0, stream>>>(deg4, boff, rowptr, shoff, dinv);

    mega_kernel<<<dim3(MQ_BLOCKS + FILL_BLOCKS), dim3(256), 0, stream>>>(
        xf, b_in, b_mid, wT, W3T, b_out, dinv, qs, row, col, shoff, rank, srcb);

    gather_kernel<<<dim3(1563), dim3(256), 0, stream>>>(rowptr, srcb, qs, dinv, out);
}